// Round 9
// baseline (1565.468 us; speedup 1.0000x reference)
//
#include <hip/hip_runtime.h>
#include <hip/hip_bf16.h>
#include <stdint.h>

// Problem constants
#define NN   16384   // nodes
#define FI   128     // in feats
#define FH   128     // hidden
#define FO   64      // out feats

// Kernel-2 tiling: BM=32 rows/block, K split in half -> 1024 blocks, 3/CU.
#define BM   32
#define BK   64
#define LDK  72          // padded bf16 leading dim
#define KHALF (NN / 2)
#define NTH  (KHALF / BK)   // 128 K-tiles per block
#define NPART 512           // colsum partial rows (one per rb; kh halves disjoint cols)

typedef float f32x4 __attribute__((ext_vector_type(4)));
typedef short s16x8 __attribute__((ext_vector_type(8)));
typedef short s16x4 __attribute__((ext_vector_type(4)));

__device__ __forceinline__ unsigned short f2bf(float f) {
    union { float f; unsigned u; } v; v.f = f;
    unsigned u = v.u;
    return (unsigned short)((u + 0x7FFFu + ((u >> 16) & 1u)) >> 16);  // RNE
}

// ---------------------------------------------------------------------------
// Kernel 1: S1T[n][k] = sum_f x[k][f] * W1[f][n], stored bf16 TRANSPOSED
// (n-major) so kernel 2 can read B-fragments with contiguous 16 B loads.
// ---------------------------------------------------------------------------
__global__ __launch_bounds__(256) void k1_s1t(const float* __restrict__ x,
                                              const float* __restrict__ W1,
                                              unsigned short* __restrict__ S1T) {
    __shared__ float w1s[FI][FH];     // [f][n], 64 KB, reads are wave-uniform (broadcast)
    __shared__ float xs[64][132];     // 64 k-rows, pad 132 -> uniform 8-way b128 (optimal)

    const int t  = threadIdx.x;
    const int b  = blockIdx.x;        // 256 blocks
    const int k0 = b * 64;

    float* wflat = &w1s[0][0];
    for (int i = t; i < FI * FH; i += 256) wflat[i] = W1[i];

    #pragma unroll
    for (int s = 0; s < 8; ++s) {
        int idx = t + 256 * s;              // 2048 float4 chunks
        int r   = idx >> 5;                 // 0..63
        int f4  = idx & 31;
        f32x4 vv = *(const f32x4*)(x + (size_t)(k0 + r) * FI + f4 * 4);
        *(f32x4*)(&xs[r][f4 * 4]) = vv;
    }
    __syncthreads();

    const int w = t >> 6;                   // wave = n-group (32 cols)
    const int l = t & 63;                   // lane = k-row

    float acc[32];
    #pragma unroll
    for (int j = 0; j < 32; ++j) acc[j] = 0.f;

    for (int f4 = 0; f4 < 32; ++f4) {
        f32x4 xv = *(const f32x4*)(&xs[l][f4 * 4]);
        #pragma unroll
        for (int e = 0; e < 4; ++e) {
            const int f = f4 * 4 + e;
            #pragma unroll
            for (int cth = 0; cth < 8; ++cth) {
                f32x4 wv = *(const f32x4*)(&w1s[f][w * 32 + cth * 4]);  // broadcast
                acc[cth * 4 + 0] += xv[e] * wv[0];
                acc[cth * 4 + 1] += xv[e] * wv[1];
                acc[cth * 4 + 2] += xv[e] * wv[2];
                acc[cth * 4 + 3] += xv[e] * wv[3];
            }
        }
    }

    const int k = k0 + l;
    #pragma unroll
    for (int j = 0; j < 32; ++j) {
        const int n = w * 32 + j;
        S1T[(size_t)n * NN + k] = f2bf(acc[j]);   // lanes -> consecutive k, coalesced
    }
}

// ---------------------------------------------------------------------------
// Kernel 2 (v9): T = adj @ S1, MFMA 16x16x32 bf16.
//
// B-staging PRIVATIZED PER WAVE: wave w only ever reads S1T rows
// w*32..w*32+31, so it stages its own rows into its own double-buffered LDS
// slab bW[w][2][32][LDK] with no inter-wave coupling.  The ONLY barrier left
// is the tiny A-tile dbuf swap (4.6 KB, 2 loads/thread) -> 1 barrier/tile,
// and B no longer contributes to barrier-phase skew.  2-deep named register
// prefetch for both A and B; raw lgkm-only barriers keep global loads in
// flight.  LDS 47 KB -> 3 blocks/CU, ~110 VGPR.
// ---------------------------------------------------------------------------
__global__ __launch_bounds__(256, 3) void k2_agg(const float* __restrict__ adj,
                                                 const unsigned short* __restrict__ S1T,
                                                 float* __restrict__ Tpart,
                                                 float* __restrict__ cpart) {
    __shared__ unsigned short aA[2][BM][LDK];      //  9,216 B (block-shared, dbuf)
    __shared__ unsigned short bW[4][2][BM][LDK];   // 36,864 B (wave-private, dbuf)
    __shared__ float cs[2][4][BK];                 //  2,048 B (dbuf)

    const int  t    = threadIdx.x;
    const int  rb   = blockIdx.x >> 1;          // row-block 0..511
    const int  kh   = blockIdx.x & 1;           // k-half
    const long m0   = (long)rb * BM;
    const long k0   = (long)kh * KHALF;
    const int  w    = t >> 6;
    const int  l    = t & 63;
    const int  ar   = t >> 4;       // A stage row 0..15 (+16)
    const int  ac4  = t & 15;       // A stage float4-col
    const int  br   = l >> 3;       // B stage row-in-group 0..7
    const int  bc   = l & 7;        // B stage 16 B chunk 0..7
    const int  m    = l & 15;
    const int  quad = l >> 4;

    f32x4 acc[2][2];
    #pragma unroll
    for (int i = 0; i < 2; ++i)
        #pragma unroll
        for (int j = 0; j < 2; ++j) acc[i][j] = (f32x4){0.f, 0.f, 0.f, 0.f};

    // two named prefetch sets: A = 2 f32x4, B = 4 s16x8 (24 VGPR per set)
    f32x4 paX0, paX1, paY0, paY1;
    s16x8 psX[4], psY[4];

#define BAR() do {                                                                \
    asm volatile("s_waitcnt lgkmcnt(0)" ::: "memory");                            \
    __builtin_amdgcn_s_barrier();                                                 \
} while (0)

#define LOAD(PA0, PA1, PS, J) do {                                                \
    const long koff_ = k0 + (long)(J) * BK;                                       \
    PA0 = *(const f32x4*)(adj + (m0 + ar) * NN + koff_ + ac4 * 4);                \
    PA1 = *(const f32x4*)(adj + (m0 + ar + 16) * NN + koff_ + ac4 * 4);           \
    _Pragma("unroll")                                                             \
    for (int g_ = 0; g_ < 4; ++g_)                                                \
        PS[g_] = *(const s16x8*)(S1T + (size_t)(w * 32 + g_ * 8 + br) * NN        \
                                 + koff_ + bc * 8);                               \
} while (0)

// stage tile J into buf SB: colsum partial (-> cs dbuf), A cvt+write
// (cooperative), B write (wave-private slab)
#define STAGE(SB, PA0, PA1, PS) do {                                              \
    f32x4 pv_;                                                                    \
    _Pragma("unroll")                                                             \
    for (int j_ = 0; j_ < 4; ++j_) {                                              \
        float p_ = PA0[j_] + PA1[j_];                                             \
        p_ += __shfl_xor(p_, 16);                                                 \
        p_ += __shfl_xor(p_, 32);                                                 \
        pv_[j_] = p_;                                                             \
    }                                                                             \
    if (l < 16) *(f32x4*)(&cs[SB][w][l * 4]) = pv_;                               \
    s16x4 q0_, q1_;                                                               \
    _Pragma("unroll")                                                             \
    for (int j_ = 0; j_ < 4; ++j_) {                                              \
        q0_[j_] = (short)f2bf(PA0[j_]);                                           \
        q1_[j_] = (short)f2bf(PA1[j_]);                                           \
    }                                                                             \
    *(s16x4*)(&aA[SB][ar][ac4 * 4])      = q0_;                                   \
    *(s16x4*)(&aA[SB][ar + 16][ac4 * 4]) = q1_;                                   \
    _Pragma("unroll")                                                             \
    for (int g_ = 0; g_ < 4; ++g_)                                                \
        *(s16x8*)(&bW[w][SB][g_ * 8 + br][bc * 8]) = PS[g_];                      \
} while (0)

// cross-wave colsum combine + one coalesced 256 B store
#define FLUSH(SB, J) do {                                                         \
    if (t < BK)                                                                   \
        cpart[(size_t)rb * NN + k0 + (long)(J) * BK + t] =                        \
            cs[SB][0][t] + cs[SB][1][t] + cs[SB][2][t] + cs[SB][3][t];            \
} while (0)

#define COMPUTE(SB) do {                                                          \
    _Pragma("unroll")                                                             \
    for (int ks = 0; ks < 2; ++ks) {                                              \
        s16x8 af_[2], bf_[2];                                                     \
        _Pragma("unroll")                                                         \
        for (int mt = 0; mt < 2; ++mt)                                            \
            af_[mt] = *(const s16x8*)(&aA[SB][mt * 16 + m][ks * 32 + quad * 8]);  \
        _Pragma("unroll")                                                         \
        for (int nt = 0; nt < 2; ++nt)                                            \
            bf_[nt] = *(const s16x8*)(&bW[w][SB][nt * 16 + m][ks * 32 + quad * 8]); \
        _Pragma("unroll")                                                         \
        for (int mt = 0; mt < 2; ++mt)                                            \
            _Pragma("unroll")                                                     \
            for (int nt = 0; nt < 2; ++nt)                                        \
                acc[mt][nt] = __builtin_amdgcn_mfma_f32_16x16x32_bf16(            \
                    af_[mt], bf_[nt], acc[mt][nt], 0, 0, 0);                      \
    }                                                                             \
} while (0)

    // ---- prologue: tile 0 staged (buf 0); tile 1 in set Y; set X refills 2 ----
    LOAD(paX0, paX1, psX, 0);
    LOAD(paY0, paY1, psY, 1);
    STAGE(0, paX0, paX1, psX);
    LOAD(paX0, paX1, psX, 2);
    BAR();

    for (int j = 0; j < NTH; j += 2) {
        // ---- tile j (even, buf 0): stage j+1 from Y into buf 1, refill Y(j+3) ----
        if (j + 1 < NTH) STAGE(1, paY0, paY1, psY);
        FLUSH(0, j);
        COMPUTE(0);
        if (j + 3 < NTH) LOAD(paY0, paY1, psY, j + 3);
        BAR();

        // ---- tile j+1 (odd, buf 1): stage j+2 from X into buf 0, refill X(j+4) ----
        if (j + 2 < NTH) STAGE(0, paX0, paX1, psX);
        FLUSH(1, j + 1);
        COMPUTE(1);
        if (j + 4 < NTH) LOAD(paX0, paX1, psX, j + 4);
        BAR();
    }

#undef BAR
#undef LOAD
#undef STAGE
#undef FLUSH
#undef COMPUTE

    // epilogue: C/D layout col=lane&15, row=quad*4+reg; this k-half's slab
    float* Tp = Tpart + (size_t)kh * NN * FH;
    #pragma unroll
    for (int mt = 0; mt < 2; ++mt)
        #pragma unroll
        for (int nt = 0; nt < 2; ++nt) {
            const int col = w * 32 + nt * 16 + m;
            #pragma unroll
            for (int r = 0; r < 4; ++r) {
                const long row = m0 + mt * 16 + quad * 4 + r;
                Tp[row * FH + col] = acc[mt][nt][r];
            }
        }
}

// ---------------------------------------------------------------------------
// Kernel 3: finish colsum c[k] = sum_p cpart[p][k] (512 partials, coalesced),
// then v[m] = sum_k c[k] * relu(Tpart0[k][m] + Tpart1[k][m] + b1[m])
// ---------------------------------------------------------------------------
__global__ __launch_bounds__(256) void k3_v(const float* __restrict__ Tpart,
                                            const float* __restrict__ cpart,
                                            const float* __restrict__ b1,
                                            float* __restrict__ v) {
    __shared__ float vp[FH];
    __shared__ float cw[4][64];
    __shared__ float cloc[64];

    const int t = threadIdx.x;
    const int b = blockIdx.x;      // 256 blocks x 64 rows
    const int w = t >> 6;
    const int l = t & 63;

    // 512-way partial reduction for this block's 64 k-rows.
    float s = 0.f;
    #pragma unroll 8
    for (int i = 0; i < NPART / 4; ++i)
        s += cpart[(size_t)(w + 4 * i) * NN + b * 64 + l];
    cw[w][l] = s;
    if (t < FH) vp[t] = 0.f;
    __syncthreads();
    if (t < 64) cloc[t] = cw[0][t] + cw[1][t] + cw[2][t] + cw[3][t];
    __syncthreads();

    const int kk = t >> 2;
    const int mq = t & 3;
    const int k  = b * 64 + kk;
    const float ck = cloc[kk];

    #pragma unroll
    for (int j4 = 0; j4 < 8; ++j4) {
        f32x4 t0 = *(const f32x4*)(Tpart + (size_t)k * FH + mq * 32 + j4 * 4);
        f32x4 t1 = *(const f32x4*)(Tpart + ((size_t)NN + k) * FH + mq * 32 + j4 * 4);
        f32x4 bv = *(const f32x4*)(b1 + mq * 32 + j4 * 4);
        #pragma unroll
        for (int e = 0; e < 4; ++e) {
            float h = t0[e] + t1[e] + bv[e];
            h = h > 0.f ? h : 0.f;
            atomicAdd(&vp[mq * 32 + j4 * 4 + e], ck * h);
        }
    }
    __syncthreads();
    if (t < FH) atomicAdd(&v[t], vp[t]);
}

// ---------------------------------------------------------------------------
// Kernel 4: pooled = v @ W2 + N*b2 ; out = pooled @ W_out + b_out
// ---------------------------------------------------------------------------
__global__ void k4_out(const float* __restrict__ v, const float* __restrict__ W2,
                       const float* __restrict__ b2, const float* __restrict__ Wout,
                       const float* __restrict__ bout, float* __restrict__ out) {
    const int j = threadIdx.x;  // 64
    float pj = (float)NN * b2[j];
    for (int mm = 0; mm < FH; ++mm) pj += v[mm] * W2[mm * FO + j];
    float s = pj * Wout[j];
    #pragma unroll
    for (int off = 32; off; off >>= 1) s += __shfl_down(s, off);
    if (j == 0) out[0] = s + bout[0];
}

// ---------------------------------------------------------------------------
extern "C" void kernel_launch(void* const* d_in, const int* in_sizes, int n_in,
                              void* d_out, int out_size, void* d_ws, size_t ws_size,
                              hipStream_t stream) {
    const float* x    = (const float*)d_in[0];
    const float* adj  = (const float*)d_in[1];
    const float* W1   = (const float*)d_in[2];
    const float* b1   = (const float*)d_in[3];
    const float* W2   = (const float*)d_in[4];
    const float* b2   = (const float*)d_in[5];
    const float* Wout = (const float*)d_in[6];
    const float* bout = (const float*)d_in[7];
    float* out = (float*)d_out;

    char* ws = (char*)d_ws;
    unsigned short* S1T = (unsigned short*)ws;                 // 4 MiB bf16 [128][16384]
    float* Tpart = (float*)(ws + (4u  << 20));                 // 16 MiB fp32 [2][16384][128]
    float* cpart = (float*)(ws + (20u << 20));                 // 32 MiB fp32 [512][16384]
    float* v     = (float*)(ws + (52u << 20));                 // 512 B fp32 [128]

    hipMemsetAsync(v, 0, 512, stream);                         // zero v only

    k1_s1t<<<256, 256, 0, stream>>>(x, W1, S1T);
    k2_agg<<<1024, 256, 0, stream>>>(adj, S1T, Tpart, cpart);
    k3_v  <<<256, 256, 0, stream>>>(Tpart, cpart, b1, v);
    k4_out<<<1, 64, 0, stream>>>(v, W2, b2, Wout, bout, out);
}

// Round 10
// 1435.306 us; speedup vs baseline: 1.0907x; 1.0907x over previous
//
#include <hip/hip_runtime.h>
#include <hip/hip_bf16.h>
#include <stdint.h>

// Problem constants
#define NN   16384   // nodes
#define FI   128     // in feats
#define FH   128     // hidden
#define FO   64      // out feats

// Kernel-2 tiling: BM=32 rows/block, BK=128 (512 B per-row bursts), K split
// in half -> 1024 blocks; 54.3 KB LDS -> 3 blocks/CU.  Best-measured config
// (R8: total 1481 us, k2 ~354 us).
#define BM   32
#define BK   128
#define LDK  136         // padded bf16 leading dim
#define KHALF (NN / 2)
#define NTH  (KHALF / BK)   // 64 K-tiles per block
#define NPART 512           // colsum partial rows (one per rb; kh halves share)

typedef float f32x4 __attribute__((ext_vector_type(4)));
typedef short s16x8 __attribute__((ext_vector_type(8)));
typedef short s16x4 __attribute__((ext_vector_type(4)));

__device__ __forceinline__ unsigned short f2bf(float f) {
    union { float f; unsigned u; } v; v.f = f;
    unsigned u = v.u;
    return (unsigned short)((u + 0x7FFFu + ((u >> 16) & 1u)) >> 16);  // RNE
}

// ---------------------------------------------------------------------------
// Kernel 1: S1T[n][k] = sum_f x[k][f] * W1[f][n], stored bf16 TRANSPOSED
// (n-major) so kernel 2 can read B-fragments with contiguous 16 B loads.
// ---------------------------------------------------------------------------
__global__ __launch_bounds__(256) void k1_s1t(const float* __restrict__ x,
                                              const float* __restrict__ W1,
                                              unsigned short* __restrict__ S1T) {
    __shared__ float w1s[FI][FH];     // [f][n], 64 KB, reads are wave-uniform (broadcast)
    __shared__ float xs[64][132];     // 64 k-rows, pad 132 -> uniform 8-way b128 (optimal)

    const int t  = threadIdx.x;
    const int b  = blockIdx.x;        // 256 blocks
    const int k0 = b * 64;

    float* wflat = &w1s[0][0];
    for (int i = t; i < FI * FH; i += 256) wflat[i] = W1[i];

    #pragma unroll
    for (int s = 0; s < 8; ++s) {
        int idx = t + 256 * s;              // 2048 float4 chunks
        int r   = idx >> 5;                 // 0..63
        int f4  = idx & 31;
        f32x4 vv = *(const f32x4*)(x + (size_t)(k0 + r) * FI + f4 * 4);
        *(f32x4*)(&xs[r][f4 * 4]) = vv;
    }
    __syncthreads();

    const int w = t >> 6;                   // wave = n-group (32 cols)
    const int l = t & 63;                   // lane = k-row

    float acc[32];
    #pragma unroll
    for (int j = 0; j < 32; ++j) acc[j] = 0.f;

    for (int f4 = 0; f4 < 32; ++f4) {
        f32x4 xv = *(const f32x4*)(&xs[l][f4 * 4]);
        #pragma unroll
        for (int e = 0; e < 4; ++e) {
            const int f = f4 * 4 + e;
            #pragma unroll
            for (int cth = 0; cth < 8; ++cth) {
                f32x4 wv = *(const f32x4*)(&w1s[f][w * 32 + cth * 4]);  // broadcast
                acc[cth * 4 + 0] += xv[e] * wv[0];
                acc[cth * 4 + 1] += xv[e] * wv[1];
                acc[cth * 4 + 2] += xv[e] * wv[2];
                acc[cth * 4 + 3] += xv[e] * wv[3];
            }
        }
    }

    const int k = k0 + l;
    #pragma unroll
    for (int j = 0; j < 32; ++j) {
        const int n = w * 32 + j;
        S1T[(size_t)n * NN + k] = f2bf(acc[j]);   // lanes -> consecutive k, coalesced
    }
}

// ---------------------------------------------------------------------------
// Kernel 2 (v8, best measured): T = adj @ S1, MFMA 16x16x32 bf16.
// Double-A / single-B LDS, 2 raw lgkm-only barriers per tile, 2-deep named
// X/Y register prefetch, cs+FLUSH colsum, BK=128.
// ---------------------------------------------------------------------------
__global__ __launch_bounds__(256, 3) void k2_agg(const float* __restrict__ adj,
                                                 const unsigned short* __restrict__ S1T,
                                                 float* __restrict__ Tpart,
                                                 float* __restrict__ cpart) {
    __shared__ unsigned short aA[2][BM][LDK];   // 17,408 B
    __shared__ unsigned short bBs[FH][LDK];     // 34,816 B
    __shared__ float cs[4][BK];                 //  2,048 B   (54.3 KB total)

    const int  t    = threadIdx.x;
    const int  rb   = blockIdx.x >> 1;          // row-block 0..511
    const int  kh   = blockIdx.x & 1;           // k-half
    const long m0   = (long)rb * BM;
    const long k0   = (long)kh * KHALF;
    const int  w    = t >> 6;
    const int  l    = t & 63;
    const int  ar   = t >> 4;       // stage row 0..15 (+16)
    const int  ac8  = t & 15;       // stage 8-float / 16-byte chunk
    const int  m    = l & 15;
    const int  quad = l >> 4;

    f32x4 acc[2][2];
    #pragma unroll
    for (int i = 0; i < 2; ++i)
        #pragma unroll
        for (int j = 0; j < 2; ++j) acc[i][j] = (f32x4){0.f, 0.f, 0.f, 0.f};

    // two named prefetch sets: A = 4 f32x4, B = 8 s16x8.  ~145 VGPR total.
    f32x4 paX[4], paY[4];
    s16x8 psX[8], psY[8];

#define BAR() do {                                                                \
    asm volatile("s_waitcnt lgkmcnt(0)" ::: "memory");                            \
    __builtin_amdgcn_s_barrier();                                                 \
} while (0)

#define LOAD(PA, PS, J) do {                                                      \
    const long koff_ = k0 + (long)(J) * BK;                                       \
    const float* ap_ = adj + (m0 + ar) * NN + koff_ + ac8 * 8;                    \
    PA[0] = *(const f32x4*)ap_;                                                   \
    PA[1] = *(const f32x4*)(ap_ + 4);                                             \
    PA[2] = *(const f32x4*)(ap_ + (size_t)16 * NN);                               \
    PA[3] = *(const f32x4*)(ap_ + (size_t)16 * NN + 4);                           \
    _Pragma("unroll")                                                             \
    for (int g_ = 0; g_ < 8; ++g_)                                                \
        PS[g_] = *(const s16x8*)(S1T + (size_t)(ar + 16 * g_) * NN + koff_ + ac8 * 8); \
} while (0)

// colsum partial (wave's 8 rows via quad-xor reduce) + cvt + A-tile LDS write
#define CSUM_STAGEA(SB, PA) do {                                                  \
    f32x4 pv0_, pv1_;                                                             \
    _Pragma("unroll")                                                             \
    for (int j_ = 0; j_ < 4; ++j_) {                                              \
        float p0_ = PA[0][j_] + PA[2][j_];                                        \
        float p1_ = PA[1][j_] + PA[3][j_];                                        \
        p0_ += __shfl_xor(p0_, 16);  p0_ += __shfl_xor(p0_, 32);                  \
        p1_ += __shfl_xor(p1_, 16);  p1_ += __shfl_xor(p1_, 32);                  \
        pv0_[j_] = p0_;  pv1_[j_] = p1_;                                          \
    }                                                                             \
    if (l < 16) {                                                                 \
        *(f32x4*)(&cs[w][l * 8])     = pv0_;                                      \
        *(f32x4*)(&cs[w][l * 8 + 4]) = pv1_;                                      \
    }                                                                             \
    s16x8 q0_, q1_;                                                               \
    _Pragma("unroll")                                                             \
    for (int j_ = 0; j_ < 4; ++j_) {                                              \
        q0_[j_]     = (short)f2bf(PA[0][j_]);                                     \
        q0_[j_ + 4] = (short)f2bf(PA[1][j_]);                                     \
        q1_[j_]     = (short)f2bf(PA[2][j_]);                                     \
        q1_[j_ + 4] = (short)f2bf(PA[3][j_]);                                     \
    }                                                                             \
    *(s16x8*)(&aA[SB][ar][ac8 * 8])      = q0_;                                   \
    *(s16x8*)(&aA[SB][ar + 16][ac8 * 8]) = q1_;                                   \
} while (0)

#define STAGEB(PS) do {                                                           \
    _Pragma("unroll")                                                             \
    for (int g_ = 0; g_ < 8; ++g_)                                                \
        *(s16x8*)(&bBs[ar + 16 * g_][ac8 * 8]) = PS[g_];                          \
} while (0)

// cross-wave colsum combine + one coalesced 512 B store
#define FLUSH(J) do {                                                             \
    if (t < BK)                                                                   \
        cpart[(size_t)rb * NN + k0 + (long)(J) * BK + t] =                        \
            cs[0][t] + cs[1][t] + cs[2][t] + cs[3][t];                            \
} while (0)

#define COMPUTE(SB) do {                                                          \
    _Pragma("unroll")                                                             \
    for (int ks = 0; ks < 4; ++ks) {                                              \
        s16x8 af_[2], bf_[2];                                                     \
        _Pragma("unroll")                                                         \
        for (int mt = 0; mt < 2; ++mt)                                            \
            af_[mt] = *(const s16x8*)(&aA[SB][mt * 16 + m][ks * 32 + quad * 8]);  \
        _Pragma("unroll")                                                         \
        for (int nt = 0; nt < 2; ++nt)                                            \
            bf_[nt] = *(const s16x8*)(&bBs[w * 32 + nt * 16 + m][ks * 32 + quad * 8]); \
        _Pragma("unroll")                                                         \
        for (int mt = 0; mt < 2; ++mt)                                            \
            _Pragma("unroll")                                                     \
            for (int nt = 0; nt < 2; ++nt)                                        \
                acc[mt][nt] = __builtin_amdgcn_mfma_f32_16x16x32_bf16(            \
                    af_[mt], bf_[nt], acc[mt][nt], 0, 0, 0);                      \
    }                                                                             \
} while (0)

    // ---- prologue: tile 0 staged, tile 1 in regs ----
    LOAD(paX, psX, 0);
    LOAD(paY, psY, 1);
    CSUM_STAGEA(0, paX);
    STAGEB(psX);
    BAR();
    FLUSH(0);
    BAR();

    for (int j = 0; j < NTH; j += 2) {
        // ---- tile j (even): aA[0] + bBs hold tile j ----
        if (j + 2 < NTH) LOAD(paX, psX, j + 2);          // X free since prev pair
        COMPUTE(0);
        CSUM_STAGEA(1, paY);                             // tile j+1 A + colsum
        BAR();                                           // waves done reading bBs(j)
        STAGEB(psY);                                     // tile j+1 B
        FLUSH(j + 1);
        BAR();                                           // bBs(j+1) visible

        // ---- tile j+1 (odd): aA[1] + bBs hold tile j+1 ----
        if (j + 3 < NTH) LOAD(paY, psY, j + 3);
        COMPUTE(1);
        if (j + 2 < NTH) CSUM_STAGEA(0, paX);            // tile j+2 A + colsum
        BAR();
        if (j + 2 < NTH) {
            STAGEB(psX);                                 // tile j+2 B
            FLUSH(j + 2);
        }
        BAR();
    }

#undef BAR
#undef LOAD
#undef CSUM_STAGEA
#undef STAGEB
#undef FLUSH
#undef COMPUTE

    // epilogue: C/D layout col=lane&15, row=quad*4+reg; this k-half's slab
    float* Tp = Tpart + (size_t)kh * NN * FH;
    #pragma unroll
    for (int mt = 0; mt < 2; ++mt)
        #pragma unroll
        for (int nt = 0; nt < 2; ++nt) {
            const int col = w * 32 + nt * 16 + m;
            #pragma unroll
            for (int r = 0; r < 4; ++r) {
                const long row = m0 + mt * 16 + quad * 4 + r;
                Tp[row * FH + col] = acc[mt][nt][r];
            }
        }
}

// ---------------------------------------------------------------------------
// Kernel 3: finish colsum c[k] = sum_p cpart[p][k] (512 partials, coalesced),
// then v[m] = sum_k c[k] * relu(Tpart0[k][m] + Tpart1[k][m] + b1[m])
// ---------------------------------------------------------------------------
__global__ __launch_bounds__(256) void k3_v(const float* __restrict__ Tpart,
                                            const float* __restrict__ cpart,
                                            const float* __restrict__ b1,
                                            float* __restrict__ v) {
    __shared__ float vp[FH];
    __shared__ float cw[4][64];
    __shared__ float cloc[64];

    const int t = threadIdx.x;
    const int b = blockIdx.x;      // 256 blocks x 64 rows
    const int w = t >> 6;
    const int l = t & 63;

    // 512-way partial reduction for this block's 64 k-rows.
    float s = 0.f;
    #pragma unroll 8
    for (int i = 0; i < NPART / 4; ++i)
        s += cpart[(size_t)(w + 4 * i) * NN + b * 64 + l];
    cw[w][l] = s;
    if (t < FH) vp[t] = 0.f;
    __syncthreads();
    if (t < 64) cloc[t] = cw[0][t] + cw[1][t] + cw[2][t] + cw[3][t];
    __syncthreads();

    const int kk = t >> 2;
    const int mq = t & 3;
    const int k  = b * 64 + kk;
    const float ck = cloc[kk];

    #pragma unroll
    for (int j4 = 0; j4 < 8; ++j4) {
        f32x4 t0 = *(const f32x4*)(Tpart + (size_t)k * FH + mq * 32 + j4 * 4);
        f32x4 t1 = *(const f32x4*)(Tpart + ((size_t)NN + k) * FH + mq * 32 + j4 * 4);
        f32x4 bv = *(const f32x4*)(b1 + mq * 32 + j4 * 4);
        #pragma unroll
        for (int e = 0; e < 4; ++e) {
            float h = t0[e] + t1[e] + bv[e];
            h = h > 0.f ? h : 0.f;
            atomicAdd(&vp[mq * 32 + j4 * 4 + e], ck * h);
        }
    }
    __syncthreads();
    if (t < FH) atomicAdd(&v[t], vp[t]);
}

// ---------------------------------------------------------------------------
// Kernel 4: pooled = v @ W2 + N*b2 ; out = pooled @ W_out + b_out
// ---------------------------------------------------------------------------
__global__ void k4_out(const float* __restrict__ v, const float* __restrict__ W2,
                       const float* __restrict__ b2, const float* __restrict__ Wout,
                       const float* __restrict__ bout, float* __restrict__ out) {
    const int j = threadIdx.x;  // 64
    float pj = (float)NN * b2[j];
    for (int mm = 0; mm < FH; ++mm) pj += v[mm] * W2[mm * FO + j];
    float s = pj * Wout[j];
    #pragma unroll
    for (int off = 32; off; off >>= 1) s += __shfl_down(s, off);
    if (j == 0) out[0] = s + bout[0];
}

// ---------------------------------------------------------------------------
extern "C" void kernel_launch(void* const* d_in, const int* in_sizes, int n_in,
                              void* d_out, int out_size, void* d_ws, size_t ws_size,
                              hipStream_t stream) {
    const float* x    = (const float*)d_in[0];
    const float* adj  = (const float*)d_in[1];
    const float* W1   = (const float*)d_in[2];
    const float* b1   = (const float*)d_in[3];
    const float* W2   = (const float*)d_in[4];
    const float* b2   = (const float*)d_in[5];
    const float* Wout = (const float*)d_in[6];
    const float* bout = (const float*)d_in[7];
    float* out = (float*)d_out;

    char* ws = (char*)d_ws;
    unsigned short* S1T = (unsigned short*)ws;                 // 4 MiB bf16 [128][16384]
    float* Tpart = (float*)(ws + (4u  << 20));                 // 16 MiB fp32 [2][16384][128]
    float* cpart = (float*)(ws + (20u << 20));                 // 32 MiB fp32 [512][16384]
    float* v     = (float*)(ws + (52u << 20));                 // 512 B fp32 [128]

    hipMemsetAsync(v, 0, 512, stream);                         // zero v only

    k1_s1t<<<256, 256, 0, stream>>>(x, W1, S1T);
    k2_agg<<<1024, 256, 0, stream>>>(adj, S1T, Tpart, cpart);
    k3_v  <<<256, 256, 0, stream>>>(Tpart, cpart, b1, v);
    k4_out<<<1, 64, 0, stream>>>(v, W2, b2, Wout, bout, out);
}